// Round 12
// baseline (4355.023 us; speedup 1.0000x reference)
//
#include <hip/hip_runtime.h>

#define D 100
#define TT 2048
#define BB 128
#define CHUNK 64
#define NCHUNK (TT / CHUNK)
#define NTHR 832  /* 13 waves: wave0 consumer, waves 1..12 producers (R5-proven) */

static __device__ __constant__ float KLO = 2.8853900817779268f;   // 2*log2(e)
static __device__ __constant__ float MKF = -2.8853900817779268f;  // -2*log2(e)

// q += dpp_shuffle(q); ctrl must be an immediate
#define DPP_ADD(q, ctrl)                                                      \
  q += __int_as_float(__builtin_amdgcn_update_dpp(                            \
      0, __float_as_int(q), ctrl, 0xF, 0xF, true))

// ---------------------------------------------------------------------------
// K1: ab2m[j] = -log2(e) * (pos_table[j] . w_ap + b0)
// ---------------------------------------------------------------------------
__global__ void k1_pos(const float* __restrict__ pos, const float* __restrict__ wap,
                       const float* __restrict__ bb, float* __restrict__ ab2m) {
  int j = blockIdx.x * blockDim.x + threadIdx.x;
  if (j < TT) {
    float a = 0.f;
    #pragma unroll 4
    for (int e = 0; e < D; ++e) a = fmaf(pos[j * D + e], wap[e], a);
    ab2m[j] = -1.4426950408889634f * (a + bb[0]);
  }
}

// ---------------------------------------------------------------------------
// R12 = R5 (552us, proven: remat-no-spill producers, WRITE=1KB) with exactly
// two edits:
//  (1) producer s-loop stride 7 -> 12: exact partition instead of ~4x
//      redundant coverage (producer VMEM+VALU /4, less contention with the
//      chain wave's SIMD and L2).
//  (2) consumer ab2m: per-step global load -> once-per-chunk row +
//      readlane(abrow_, s)  (CHUNK == 64 == wave width).
// Everything else byte-identical to R5 to protect its allocator behavior.
// R10/R11 lesson: LDS-staging redesigns regress (producer LDS latency chains,
// serial stager, 8-way ring conflicts); the chain's serial floor is
// ~280-340us and R5's structure is closest to it.
// ---------------------------------------------------------------------------
__global__ void __launch_bounds__(NTHR)
sp_scan(const float* __restrict__ h, const float* __restrict__ dv,
        const float* __restrict__ w_c, const float* __restrict__ w_s,
        const float* __restrict__ w_r, const float* __restrict__ ab2m,
        float* __restrict__ out) {
  __shared__ float gbuf[2][CHUNK][128];  // 64 KiB, double-buffered g chunks
  __shared__ float crow_s[128];
  const int b = blockIdx.x;
  const int tid = (int)threadIdx.x;
  const int lane = tid & 63;
  const int wvu = __builtin_amdgcn_readfirstlane(tid) >> 6;  // uniform wave id

  // ---- phase 1: crow[e] = w_c[e] + (d_b @ w_s)[e] - colsum(w_r)[e] --------
  if (tid < 128) {
    float acc = 0.f;
    if (tid < D) {
      float a1 = 0.f, a2 = 0.f;
      for (int dd = 0; dd < D; ++dd) {
        a1 = fmaf(dv[b * D + dd], w_s[dd * D + tid], a1);
        a2 += w_r[dd * D + tid];
      }
      acc = w_c[tid] + a1 - a2;
    }
    crow_s[tid] = acc;
  }
  __syncthreads();

  // ---- phase 2: producers pull their two w_r rows into registers ----------
  float wlo[D], whi[D];
  if (wvu != 0) {
    const float* rl = w_r + lane * D;
    #pragma unroll
    for (int e = 0; e < D; ++e) wlo[e] = rl[e];
    if (lane < 36) {
      const float* rh = w_r + (lane + 64) * D;
      #pragma unroll
      for (int e = 0; e < D; ++e) whi[e] = rh[e];
    } else if (lane == 36) {
      #pragma unroll
      for (int e = 0; e < D; ++e) whi[e] = crow_s[e];  // synthetic row 100
    } else {
      #pragma unroll
      for (int e = 0; e < D; ++e) whi[e] = 0.f;        // pad rows 101..127
    }
  }
  __syncthreads();

  const float* hb = h + (size_t)b * TT * D;

  // consumer state
  float Slo = 0.f, Shi = 0.f, c = 0.f, hlp = 0.f, hhp = 0.f, pout = 0.f;
  float hlb[8], hhb[8], abrow_ = 0.f;

  // ---- phase 3: prime — producers fill chunk 0; consumer prefetches h -----
  if (wvu == 0) {
    __builtin_amdgcn_s_setprio(1);  // favor the latency-critical wave
    abrow_ = ab2m[lane];            // chunk 0's ab row (lane == s)
    #pragma unroll
    for (int i = 0; i < 8; ++i) {
      float sc = (i == 0) ? 0.f : KLO;  // mask t=0 state update
      hlb[i] = sc * hb[(size_t)i * D + lane];
      hhb[i] = (lane < 36) ? sc * hb[(size_t)i * D + lane + 64] : 0.f;
    }
  } else {
    for (int s = wvu - 1; s < CHUNK; s += 12) {  // exact 12-way partition
      const float4* hr = (const float4*)(hb + (size_t)s * D);
      float a0 = 0.f, a1 = 0.f, c0 = 0.f, c1 = 0.f;
      #pragma unroll
      for (int qd = 0; qd < 25; ++qd) {
        const float4 hv = hr[qd];
        a0 = fmaf(hv.x, wlo[4 * qd + 0], a0);
        a1 = fmaf(hv.y, wlo[4 * qd + 1], a1);
        a0 = fmaf(hv.z, wlo[4 * qd + 2], a0);
        a1 = fmaf(hv.w, wlo[4 * qd + 3], a1);
        c0 = fmaf(hv.x, whi[4 * qd + 0], c0);
        c1 = fmaf(hv.y, whi[4 * qd + 1], c1);
        c0 = fmaf(hv.z, whi[4 * qd + 2], c0);
        c1 = fmaf(hv.w, whi[4 * qd + 3], c1);
      }
      gbuf[0][s][lane] = a0 + a1;
      gbuf[0][s][lane + 64] = c0 + c1;
    }
  }
  __syncthreads();

  // ---- main loop: 32 chunks of 64 steps -----------------------------------
  for (int cc = 0; cc < NCHUNK; ++cc) {
    if (wvu == 0) {
      float(*gb)[128] = gbuf[cc & 1];
      float g0l = gb[0][lane], g0h = gb[0][lane + 64];
      float g1l = gb[1][lane], g1h = gb[1][lane + 64];
      const int ncc = (cc + 1 < NCHUNK) ? cc + 1 : cc;
      float abn = ab2m[ncc * CHUNK + lane];  // next chunk's ab row (off-chain)
      #pragma unroll 8
      for (int s = 0; s < CHUNK; ++s) {
        const int j = cc * CHUNK + s;
        // grab prefetched h (used NEXT iter)
        float hlv = hlb[s & 7], hhv = hhb[s & 7];
        // refill slot with j+8 (clamped; clamped values are never consumed)
        {
          int jn = j + 8;
          if (jn >= TT) jn = TT - 1;
          const size_t off = (size_t)jn * D;
          hlb[s & 7] = KLO * hb[off + lane];
          hhb[s & 7] = (lane < 36) ? KLO * hb[off + lane + 64] : 0.f;
        }
        // LDS g prefetch, distance 2
        float g2l = 0.f, g2h = 0.f;
        if (s < CHUNK - 2) { g2l = gb[s + 2][lane]; g2h = gb[s + 2][lane + 64]; }

        // ---- the sequential chain ----
        Slo = fmaf(hlp, c, Slo);          // deferred state update (h_{j-1}*p_{j-1})
        Shi = fmaf(hhp, c, Shi);
        float rlo = __builtin_amdgcn_rcpf(1.f + __builtin_amdgcn_exp2f(Slo));
        float rhi = __builtin_amdgcn_rcpf(1.f + __builtin_amdgcn_exp2f(Shi));
        float q = rlo * g0l;
        q = fmaf(rhi, g0h, q);
        DPP_ADD(q, 0xB1);   // + lane^1   (quad_perm [1,0,3,2])
        DPP_ADD(q, 0x4E);   // + lane^2   (quad_perm [2,3,0,1])
        DPP_ADD(q, 0x141);  // + lane^7   (row_half_mirror) -> 8-sums
        DPP_ADD(q, 0x140);  // + lane^15  (row_mirror)      -> 16-sums
        const int qi = __float_as_int(q);
        float ra = __int_as_float(__builtin_amdgcn_readlane(qi, 0)) +
                   __int_as_float(__builtin_amdgcn_readlane(qi, 16));
        float rb = __int_as_float(__builtin_amdgcn_readlane(qi, 32)) +
                   __int_as_float(__builtin_amdgcn_readlane(qi, 48));
        float R = ra + rb;                      // = sum_d r_d * g_d
        float abv = __int_as_float(
            __builtin_amdgcn_readlane(__float_as_int(abrow_), s));
        float nz = fmaf(MKF, R, abv);           // -log2e * z
        float p = __builtin_amdgcn_rcpf(1.f + __builtin_amdgcn_exp2f(nz));
        pout = (lane == s) ? p : pout;
        c = p;
        hlp = hlv;
        hhp = hhv;
        g0l = g1l; g0h = g1h; g1l = g2l; g1h = g2h;
      }
      out[(size_t)b * TT + cc * CHUNK + lane] = pout;
      abrow_ = abn;
    } else if (cc + 1 < NCHUNK) {
      float(*gw)[128] = gbuf[(cc + 1) & 1];
      for (int s = wvu - 1; s < CHUNK; s += 12) {  // exact 12-way partition
        const int j = (cc + 1) * CHUNK + s;
        const float4* hr = (const float4*)(hb + (size_t)j * D);
        float a0 = 0.f, a1 = 0.f, c0 = 0.f, c1 = 0.f;
        #pragma unroll
        for (int qd = 0; qd < 25; ++qd) {
          const float4 hv = hr[qd];
          a0 = fmaf(hv.x, wlo[4 * qd + 0], a0);
          a1 = fmaf(hv.y, wlo[4 * qd + 1], a1);
          a0 = fmaf(hv.z, wlo[4 * qd + 2], a0);
          a1 = fmaf(hv.w, wlo[4 * qd + 3], a1);
          c0 = fmaf(hv.x, whi[4 * qd + 0], c0);
          c1 = fmaf(hv.y, whi[4 * qd + 1], c1);
          c0 = fmaf(hv.z, whi[4 * qd + 2], c0);
          c1 = fmaf(hv.w, whi[4 * qd + 3], c1);
        }
        gw[s][lane] = a0 + a1;
        gw[s][lane + 64] = c0 + c1;
      }
    }
    __syncthreads();
  }
}

extern "C" void kernel_launch(void* const* d_in, const int* in_sizes, int n_in,
                              void* d_out, int out_size, void* d_ws, size_t ws_size,
                              hipStream_t stream) {
  const float* h   = (const float*)d_in[0];
  const float* dv  = (const float*)d_in[1];
  const float* w_c = (const float*)d_in[2];
  const float* w_s = (const float*)d_in[3];
  const float* w_r = (const float*)d_in[4];
  const float* pos = (const float*)d_in[5];
  const float* wap = (const float*)d_in[6];
  const float* bb  = (const float*)d_in[7];
  float* out = (float*)d_out;
  float* ab2m = (float*)d_ws;  // 2048 floats

  hipLaunchKernelGGL(k1_pos, dim3(TT / 256), dim3(256), 0, stream, pos, wap, bb, ab2m);
  hipLaunchKernelGGL(sp_scan, dim3(BB), dim3(NTHR), 0, stream,
                     h, dv, w_c, w_s, w_r, ab2m, out);
}